// Round 8
// baseline (111.724 us; speedup 1.0000x reference)
//
#include <hip/hip_runtime.h>

// DIN attention pooling — round 8: block = one b, wave = quarter of tiles.
//   Wb[e][h] = (W1b-W1c)[e][h] + q_e*W1d[e][h];  qh[h] = b1[h] + q @ (W1a+W1c)
//   H = sig(K@Wb + qh); G = sig(H@W2 + b2); s = G@W3 + b3 (masked); out = s^T K
// R8: grid 2048 (quarter-split waves), keys prefetch restored, W2^T staged in
// block LDS (stride 104, one barrier), block pool-reduce + plain store (no
// atomics/memset). Slab/W2 pads cover all MFMA read overhangs with zeros.

constexpr int Bn = 2048, Tn = 200, En = 64;
constexpr int HS_W  = 84;                // H slab stride (f16)
constexpr int HSLAB = 16 * HS_W + 48;    // 1392: covers aH2 row-15 read to 1388
constexpr int W2_W  = 104;               // W2T LDS stride (208B = 13 quads, odd)
constexpr int W2SZ  = 48 * W2_W + 32;    // pad: c=47 read overhangs to 5016

typedef _Float16 f16;
typedef _Float16 f16x8 __attribute__((ext_vector_type(8)));
typedef float f32x4 __attribute__((ext_vector_type(4)));

__device__ __align__(16) f16 g_wkf[80 * 64];    // [h][e]  W1b - W1c
__device__ __align__(16) f16 g_wqf[80 * 64];    // [h][e]  W1d
__device__ __align__(16) f16 g_wsumT[80 * 64];  // [h][e]  W1a + W1c
__device__ __align__(16) f16 g_w2t[48 * 96];    // [j][h]  W2^T, zeros j>=40 or h>=80

__device__ __forceinline__ float fsig(float x) {
  return __fdividef(1.0f, 1.0f + __expf(-x));
}

__global__ __launch_bounds__(256) void din_prep(const float* __restrict__ W1,
                                                const float* __restrict__ W2) {
  int idx = blockIdx.x * 256 + threadIdx.x;   // grid 20 -> 5120
  if (idx < 5120) {
    int h = idx >> 6, e = idx & 63;
    float wa = W1[e * 80 + h], wb = W1[(64 + e) * 80 + h];
    float wc = W1[(128 + e) * 80 + h], wd = W1[(192 + e) * 80 + h];
    g_wkf[idx] = (f16)(wb - wc);
    g_wqf[idx] = (f16)wd;
    g_wsumT[idx] = (f16)(wa + wc);
  }
  if (idx < 4608) {
    int j = idx / 96, h = idx - j * 96;
    g_w2t[idx] = (h < 80 && j < 40) ? (f16)W2[h * 40 + j] : (f16)0.0f;
  }
}

__global__ __launch_bounds__(256, 4) void din_main(
    const float* __restrict__ query,
    const float* __restrict__ keys,
    const int*   __restrict__ keys_length,
    const float* __restrict__ b1,
    const float* __restrict__ b2,
    const float* __restrict__ W3,
    const float* __restrict__ b3,
    float* __restrict__ out)
{
  __shared__ __align__(16) f16 sH[4][HSLAB];   // 11,136 B
  __shared__ __align__(16) f16 sW2[W2SZ];      // 10,048 B
  __shared__ float sSw[4][16];                 //    256 B
  __shared__ float sTmp[4][64];                //  1,024 B
  // total ~22.5 KB

  const int tid = threadIdx.x;
  const int lane = tid & 63;
  const int wid = tid >> 6;
  const int l15 = lane & 15;
  const int l4  = lane >> 4;

  const int b = blockIdx.x;
  const float* qp = query + (size_t)b * En;
  const float* kb = keys + (size_t)b * Tn * En;
  const int len = keys_length[b];
  const float b3v = b3[0];

  f16* hs = sH[wid];

  // ---- zero own H slab (cols 80..95 + overhang pad must read 0.0) ----
  const f16x8 zf = (f16x8)(f16)0.0f;
  for (int i = lane * 8; i < HSLAB; i += 512) *(f16x8*)&hs[i] = zf;

  // ---- cooperative W2^T copy into LDS (stride 104) + zero the tail pad ----
  for (int i = tid; i < 576; i += 256) {
    int j = i / 12, hq = (i % 12) * 8;
    *(f16x8*)&sW2[j * W2_W + hq] = *(const f16x8*)&g_w2t[j * 96 + hq];
  }
  if (tid < 4) *(f16x8*)&sW2[48 * W2_W + tid * 8] = zf;
  __syncthreads();

  // ---- q fragments (f16) ----
  f16x8 qf0, qf1;
  {
    float4 qa = *(const float4*)(qp + l4 * 8);
    float4 qb = *(const float4*)(qp + l4 * 8 + 4);
    float4 qc = *(const float4*)(qp + 32 + l4 * 8);
    float4 qd = *(const float4*)(qp + 32 + l4 * 8 + 4);
    qf0 = (f16x8){(f16)qa.x,(f16)qa.y,(f16)qa.z,(f16)qa.w,
                  (f16)qb.x,(f16)qb.y,(f16)qb.z,(f16)qb.w};
    qf1 = (f16x8){(f16)qc.x,(f16)qc.y,(f16)qc.z,(f16)qc.w,
                  (f16)qd.x,(f16)qd.y,(f16)qd.z,(f16)qd.w};
  }

  // ---- qh[c] = b1[c] + q @ wsum[:,c] via VALU dot + shfl over l4 ----
  float qhv[5];
  #pragma unroll
  for (int n = 0; n < 5; ++n) {
    int c = n * 16 + l15;
    f16x8 ws0 = *(const f16x8*)&g_wsumT[c * 64 + l4 * 8];
    f16x8 ws1 = *(const f16x8*)&g_wsumT[c * 64 + 32 + l4 * 8];
    float p = 0.f;
    #pragma unroll
    for (int j = 0; j < 8; ++j)
      p += (float)qf0[j] * (float)ws0[j] + (float)qf1[j] * (float)ws1[j];
    p += __shfl_xor(p, 16, 64);
    p += __shfl_xor(p, 32, 64);
    qhv[n] = p + b1[c];
  }

  // ---- L1 B-fragments: Wb = wk + q*wqk (elementwise f16) ----
  f16x8 bf0[5], bf1[5];
  #pragma unroll
  for (int n = 0; n < 5; ++n) {
    int c = n * 16 + l15;
    bf0[n] = *(const f16x8*)&g_wkf[c * 64 + l4 * 8]
           + qf0 * *(const f16x8*)&g_wqf[c * 64 + l4 * 8];
    bf1[n] = *(const f16x8*)&g_wkf[c * 64 + 32 + l4 * 8]
           + qf1 * *(const f16x8*)&g_wqf[c * 64 + 32 + l4 * 8];
  }

  // ---- per-col constants for L2/L3 ----
  float b2v[3], w3v[3];
  #pragma unroll
  for (int n = 0; n < 3; ++n) {
    int c = n * 16 + l15;
    b2v[n] = (c < 40) ? b2[c] : 0.0f;
    w3v[n] = (c < 40) ? W3[c] : 0.0f;
  }

  float poolA[8] = {0,0,0,0,0,0,0,0};
  float poolB[8] = {0,0,0,0,0,0,0,0};

  // ---- this wave's tile range: 4/3/3/3 split of 13 tiles ----
  const int mts = (wid == 0) ? 0 : 3 * wid + 1;
  const int mte = mts + ((wid == 0) ? 4 : 3);

  // ---- prefetch first tile's keys rows ----
  float4 p0, p1, p2, p3;
  {
    int r = mts * 16 + l15; int rc = r < Tn ? r : Tn - 1;
    const float* kr = kb + rc * 64;
    p0 = *(const float4*)(kr + l4 * 8);
    p1 = *(const float4*)(kr + l4 * 8 + 4);
    p2 = *(const float4*)(kr + 32 + l4 * 8);
    p3 = *(const float4*)(kr + 32 + l4 * 8 + 4);
  }

  for (int mt = mts; mt < mte; ++mt) {
    f16x8 ka = (f16x8){(f16)p0.x,(f16)p0.y,(f16)p0.z,(f16)p0.w,
                       (f16)p1.x,(f16)p1.y,(f16)p1.z,(f16)p1.w};
    f16x8 kc = (f16x8){(f16)p2.x,(f16)p2.y,(f16)p2.z,(f16)p2.w,
                       (f16)p3.x,(f16)p3.y,(f16)p3.z,(f16)p3.w};
    // issue next tile's loads under this tile's compute
    if (mt + 1 < mte) {
      int r = (mt + 1) * 16 + l15; int rc = r < Tn ? r : Tn - 1;
      const float* kr = kb + rc * 64;
      p0 = *(const float4*)(kr + l4 * 8);
      p1 = *(const float4*)(kr + l4 * 8 + 4);
      p2 = *(const float4*)(kr + 32 + l4 * 8);
      p3 = *(const float4*)(kr + 32 + l4 * 8 + 4);
    }

    // L1 + sigmoid -> H slab, per n (acc liveness = 4)
    #pragma unroll
    for (int n = 0; n < 5; ++n) {
      f32x4 acc = {0.f, 0.f, 0.f, 0.f};
      acc = __builtin_amdgcn_mfma_f32_16x16x32_f16(ka, bf0[n], acc, 0, 0, 0);
      acc = __builtin_amdgcn_mfma_f32_16x16x32_f16(kc, bf1[n], acc, 0, 0, 0);
      int c = n * 16 + l15;
      #pragma unroll
      for (int i = 0; i < 4; ++i)
        hs[(l4 * 4 + i) * HS_W + c] = (f16)fsig(acc[i] + qhv[n]);
    }
    // H^T A-frags
    f16x8 aH0 = *(const f16x8*)&hs[l15 * HS_W + l4 * 8];
    f16x8 aH1 = *(const f16x8*)&hs[l15 * HS_W + 32 + l4 * 8];
    f16x8 aH2 = *(const f16x8*)&hs[l15 * HS_W + 64 + l4 * 8];

    // L2 (B-frags from block LDS) + sigmoid + W3 dot
    float sc[4] = {0.f, 0.f, 0.f, 0.f};
    #pragma unroll
    for (int n = 0; n < 3; ++n) {
      int c = n * 16 + l15;
      f32x4 acc = {0.f, 0.f, 0.f, 0.f};
      acc = __builtin_amdgcn_mfma_f32_16x16x32_f16(aH0, *(const f16x8*)&sW2[c * W2_W + l4 * 8], acc, 0, 0, 0);
      acc = __builtin_amdgcn_mfma_f32_16x16x32_f16(aH1, *(const f16x8*)&sW2[c * W2_W + 32 + l4 * 8], acc, 0, 0, 0);
      acc = __builtin_amdgcn_mfma_f32_16x16x32_f16(aH2, *(const f16x8*)&sW2[c * W2_W + 64 + l4 * 8], acc, 0, 0, 0);
      #pragma unroll
      for (int i = 0; i < 4; ++i)
        sc[i] += fsig(acc[i] + b2v[n]) * w3v[n];
    }
    // reduce score over the 16 cols held across l15
    #pragma unroll
    for (int m = 1; m < 16; m <<= 1) {
      #pragma unroll
      for (int i = 0; i < 4; ++i) sc[i] += __shfl_xor(sc[i], m, 64);
    }
    if (l15 == 0) {
      #pragma unroll
      for (int i = 0; i < 4; ++i) {
        int rr = mt * 16 + l4 * 4 + i;
        sSw[wid][l4 * 4 + i] = (rr < len) ? sc[i] + b3v : 0.0f;
      }
    }
    // broadcast this lane's row score (same-wave LDS); pool with live frags
    float sv = sSw[wid][l15];
    #pragma unroll
    for (int j = 0; j < 8; ++j) {
      poolA[j] += sv * (float)ka[j];
      poolB[j] += sv * (float)kc[j];
    }
  }

  // ---- reduce pooling over the 16 rows (l15) of each l4 group ----
  #pragma unroll
  for (int m = 1; m < 16; m <<= 1) {
    #pragma unroll
    for (int j = 0; j < 8; ++j) {
      poolA[j] += __shfl_xor(poolA[j], m, 64);
      poolB[j] += __shfl_xor(poolB[j], m, 64);
    }
  }
  if (l15 == 0) {
    #pragma unroll
    for (int j = 0; j < 8; ++j) {
      sTmp[wid][l4 * 8 + j] = poolA[j];
      sTmp[wid][32 + l4 * 8 + j] = poolB[j];
    }
  }
  __syncthreads();
  if (tid < En)
    out[(size_t)b * En + tid] =
        sTmp[0][tid] + sTmp[1][tid] + sTmp[2][tid] + sTmp[3][tid];
}

extern "C" void kernel_launch(void* const* d_in, const int* in_sizes, int n_in,
                              void* d_out, int out_size, void* d_ws, size_t ws_size,
                              hipStream_t stream) {
  const float* query       = (const float*)d_in[0];
  const float* keys        = (const float*)d_in[1];
  const int*   keys_length = (const int*)d_in[2];
  const float* W1 = (const float*)d_in[3];
  const float* b1 = (const float*)d_in[4];
  const float* W2 = (const float*)d_in[5];
  const float* b2 = (const float*)d_in[6];
  const float* W3 = (const float*)d_in[7];
  const float* b3 = (const float*)d_in[8];
  float* out = (float*)d_out;

  hipLaunchKernelGGL(din_prep, dim3(20), dim3(256), 0, stream, W1, W2);
  hipLaunchKernelGGL(din_main, dim3(Bn), dim3(256), 0, stream,
                     query, keys, keys_length, b1, b2, W3, b3, out);
}

// Round 9
// 71.857 us; speedup vs baseline: 1.5548x; 1.5548x over previous
//
#include <hip/hip_runtime.h>

// DIN attention pooling — round 9: R8 structure, register bound fixed.
//   Wb[e][h] = (W1b-W1c)[e][h] + q_e*W1d[e][h];  qh[h] = b1[h] + q @ (W1a+W1c)
//   H = sig(K@Wb + qh); G = sig(H@W2 + b2); s = G@W3 + b3 (masked); out = s^T K
// Empirical (R6/R7/R8): __launch_bounds__(256,4) => 128-reg unified budget,
// compiler splits 64 VGPR + AGPR and SPILLS (100MB scratch writes).
// (256,3) => 170-reg budget, spill-free. Keep (256,3).

constexpr int Bn = 2048, Tn = 200, En = 64;
constexpr int HS_W  = 84;                // H slab stride (f16)
constexpr int HSLAB = 16 * HS_W + 48;    // 1392: covers aH2 row-15 read to 1388
constexpr int W2_W  = 104;               // W2T LDS stride (208B = 13 quads, odd)
constexpr int W2SZ  = 48 * W2_W + 32;    // pad: c=47 read overhangs to 5016

typedef _Float16 f16;
typedef _Float16 f16x8 __attribute__((ext_vector_type(8)));
typedef float f32x4 __attribute__((ext_vector_type(4)));

__device__ __align__(16) f16 g_wkf[80 * 64];    // [h][e]  W1b - W1c
__device__ __align__(16) f16 g_wqf[80 * 64];    // [h][e]  W1d
__device__ __align__(16) f16 g_wsumT[80 * 64];  // [h][e]  W1a + W1c
__device__ __align__(16) f16 g_w2t[48 * 96];    // [j][h]  W2^T, zeros j>=40 or h>=80

__device__ __forceinline__ float fsig(float x) {
  return __fdividef(1.0f, 1.0f + __expf(-x));
}

__global__ __launch_bounds__(256) void din_prep(const float* __restrict__ W1,
                                                const float* __restrict__ W2) {
  int idx = blockIdx.x * 256 + threadIdx.x;   // grid 20 -> 5120
  if (idx < 5120) {
    int h = idx >> 6, e = idx & 63;
    float wa = W1[e * 80 + h], wb = W1[(64 + e) * 80 + h];
    float wc = W1[(128 + e) * 80 + h], wd = W1[(192 + e) * 80 + h];
    g_wkf[idx] = (f16)(wb - wc);
    g_wqf[idx] = (f16)wd;
    g_wsumT[idx] = (f16)(wa + wc);
  }
  if (idx < 4608) {
    int j = idx / 96, h = idx - j * 96;
    g_w2t[idx] = (h < 80 && j < 40) ? (f16)W2[h * 40 + j] : (f16)0.0f;
  }
}

__global__ __launch_bounds__(256, 3) void din_main(
    const float* __restrict__ query,
    const float* __restrict__ keys,
    const int*   __restrict__ keys_length,
    const float* __restrict__ b1,
    const float* __restrict__ b2,
    const float* __restrict__ W3,
    const float* __restrict__ b3,
    float* __restrict__ out)
{
  __shared__ __align__(16) f16 sH[4][HSLAB];   // 11,136 B
  __shared__ __align__(16) f16 sW2[W2SZ];      // 10,048 B
  __shared__ float sSw[4][16];                 //    256 B
  __shared__ float sTmp[4][64];                //  1,024 B

  const int tid = threadIdx.x;
  const int lane = tid & 63;
  const int wid = tid >> 6;
  const int l15 = lane & 15;
  const int l4  = lane >> 4;

  const int b = blockIdx.x;
  const float* qp = query + (size_t)b * En;
  const float* kb = keys + (size_t)b * Tn * En;
  const int len = keys_length[b];
  const float b3v = b3[0];

  f16* hs = sH[wid];

  // ---- zero own H slab (cols 80..95 + overhang pad must read 0.0) ----
  const f16x8 zf = (f16x8)(f16)0.0f;
  for (int i = lane * 8; i < HSLAB; i += 512) *(f16x8*)&hs[i] = zf;

  // ---- cooperative W2^T copy into LDS (stride 104) + zero the tail pad ----
  for (int i = tid; i < 576; i += 256) {
    int j = i / 12, hq = (i % 12) * 8;
    *(f16x8*)&sW2[j * W2_W + hq] = *(const f16x8*)&g_w2t[j * 96 + hq];
  }
  if (tid < 4) *(f16x8*)&sW2[48 * W2_W + tid * 8] = zf;
  __syncthreads();

  // ---- q fragments (f16) ----
  f16x8 qf0, qf1;
  {
    float4 qa = *(const float4*)(qp + l4 * 8);
    float4 qb = *(const float4*)(qp + l4 * 8 + 4);
    float4 qc = *(const float4*)(qp + 32 + l4 * 8);
    float4 qd = *(const float4*)(qp + 32 + l4 * 8 + 4);
    qf0 = (f16x8){(f16)qa.x,(f16)qa.y,(f16)qa.z,(f16)qa.w,
                  (f16)qb.x,(f16)qb.y,(f16)qb.z,(f16)qb.w};
    qf1 = (f16x8){(f16)qc.x,(f16)qc.y,(f16)qc.z,(f16)qc.w,
                  (f16)qd.x,(f16)qd.y,(f16)qd.z,(f16)qd.w};
  }

  // ---- qh[c] = b1[c] + q @ wsum[:,c] via VALU dot + shfl over l4 ----
  float qhv[5];
  #pragma unroll
  for (int n = 0; n < 5; ++n) {
    int c = n * 16 + l15;
    f16x8 ws0 = *(const f16x8*)&g_wsumT[c * 64 + l4 * 8];
    f16x8 ws1 = *(const f16x8*)&g_wsumT[c * 64 + 32 + l4 * 8];
    float p = 0.f;
    #pragma unroll
    for (int j = 0; j < 8; ++j)
      p += (float)qf0[j] * (float)ws0[j] + (float)qf1[j] * (float)ws1[j];
    p += __shfl_xor(p, 16, 64);
    p += __shfl_xor(p, 32, 64);
    qhv[n] = p + b1[c];
  }

  // ---- L1 B-fragments: Wb = wk + q*wqk (elementwise f16) ----
  f16x8 bf0[5], bf1[5];
  #pragma unroll
  for (int n = 0; n < 5; ++n) {
    int c = n * 16 + l15;
    bf0[n] = *(const f16x8*)&g_wkf[c * 64 + l4 * 8]
           + qf0 * *(const f16x8*)&g_wqf[c * 64 + l4 * 8];
    bf1[n] = *(const f16x8*)&g_wkf[c * 64 + 32 + l4 * 8]
           + qf1 * *(const f16x8*)&g_wqf[c * 64 + 32 + l4 * 8];
  }

  // ---- per-col constants for L2/L3 ----
  float b2v[3], w3v[3];
  #pragma unroll
  for (int n = 0; n < 3; ++n) {
    int c = n * 16 + l15;
    b2v[n] = (c < 40) ? b2[c] : 0.0f;
    w3v[n] = (c < 40) ? W3[c] : 0.0f;
  }

  float poolA[8] = {0,0,0,0,0,0,0,0};
  float poolB[8] = {0,0,0,0,0,0,0,0};

  // ---- this wave's tile range: 4/3/3/3 split of 13 tiles ----
  const int mts = (wid == 0) ? 0 : 3 * wid + 1;
  const int mte = mts + ((wid == 0) ? 4 : 3);

  // ---- prefetch first tile's keys rows ----
  float4 p0, p1, p2, p3;
  {
    int r = mts * 16 + l15; int rc = r < Tn ? r : Tn - 1;
    const float* kr = kb + rc * 64;
    p0 = *(const float4*)(kr + l4 * 8);
    p1 = *(const float4*)(kr + l4 * 8 + 4);
    p2 = *(const float4*)(kr + 32 + l4 * 8);
    p3 = *(const float4*)(kr + 32 + l4 * 8 + 4);
  }

  for (int mt = mts; mt < mte; ++mt) {
    f16x8 ka = (f16x8){(f16)p0.x,(f16)p0.y,(f16)p0.z,(f16)p0.w,
                       (f16)p1.x,(f16)p1.y,(f16)p1.z,(f16)p1.w};
    f16x8 kc = (f16x8){(f16)p2.x,(f16)p2.y,(f16)p2.z,(f16)p2.w,
                       (f16)p3.x,(f16)p3.y,(f16)p3.z,(f16)p3.w};
    // issue next tile's loads under this tile's compute
    if (mt + 1 < mte) {
      int r = (mt + 1) * 16 + l15; int rc = r < Tn ? r : Tn - 1;
      const float* kr = kb + rc * 64;
      p0 = *(const float4*)(kr + l4 * 8);
      p1 = *(const float4*)(kr + l4 * 8 + 4);
      p2 = *(const float4*)(kr + 32 + l4 * 8);
      p3 = *(const float4*)(kr + 32 + l4 * 8 + 4);
    }

    // L1 + sigmoid -> H slab, per n (acc liveness = 4)
    #pragma unroll
    for (int n = 0; n < 5; ++n) {
      f32x4 acc = {0.f, 0.f, 0.f, 0.f};
      acc = __builtin_amdgcn_mfma_f32_16x16x32_f16(ka, bf0[n], acc, 0, 0, 0);
      acc = __builtin_amdgcn_mfma_f32_16x16x32_f16(kc, bf1[n], acc, 0, 0, 0);
      int c = n * 16 + l15;
      #pragma unroll
      for (int i = 0; i < 4; ++i)
        hs[(l4 * 4 + i) * HS_W + c] = (f16)fsig(acc[i] + qhv[n]);
    }
    // H^T A-frags
    f16x8 aH0 = *(const f16x8*)&hs[l15 * HS_W + l4 * 8];
    f16x8 aH1 = *(const f16x8*)&hs[l15 * HS_W + 32 + l4 * 8];
    f16x8 aH2 = *(const f16x8*)&hs[l15 * HS_W + 64 + l4 * 8];

    // L2 (B-frags from block LDS) + sigmoid + W3 dot
    float sc[4] = {0.f, 0.f, 0.f, 0.f};
    #pragma unroll
    for (int n = 0; n < 3; ++n) {
      int c = n * 16 + l15;
      f32x4 acc = {0.f, 0.f, 0.f, 0.f};
      acc = __builtin_amdgcn_mfma_f32_16x16x32_f16(aH0, *(const f16x8*)&sW2[c * W2_W + l4 * 8], acc, 0, 0, 0);
      acc = __builtin_amdgcn_mfma_f32_16x16x32_f16(aH1, *(const f16x8*)&sW2[c * W2_W + 32 + l4 * 8], acc, 0, 0, 0);
      acc = __builtin_amdgcn_mfma_f32_16x16x32_f16(aH2, *(const f16x8*)&sW2[c * W2_W + 64 + l4 * 8], acc, 0, 0, 0);
      #pragma unroll
      for (int i = 0; i < 4; ++i)
        sc[i] += fsig(acc[i] + b2v[n]) * w3v[n];
    }
    // reduce score over the 16 cols held across l15
    #pragma unroll
    for (int m = 1; m < 16; m <<= 1) {
      #pragma unroll
      for (int i = 0; i < 4; ++i) sc[i] += __shfl_xor(sc[i], m, 64);
    }
    if (l15 == 0) {
      #pragma unroll
      for (int i = 0; i < 4; ++i) {
        int rr = mt * 16 + l4 * 4 + i;
        sSw[wid][l4 * 4 + i] = (rr < len) ? sc[i] + b3v : 0.0f;
      }
    }
    // broadcast this lane's row score (same-wave LDS); pool with live frags
    float sv = sSw[wid][l15];
    #pragma unroll
    for (int j = 0; j < 8; ++j) {
      poolA[j] += sv * (float)ka[j];
      poolB[j] += sv * (float)kc[j];
    }
  }

  // ---- reduce pooling over the 16 rows (l15) of each l4 group ----
  #pragma unroll
  for (int m = 1; m < 16; m <<= 1) {
    #pragma unroll
    for (int j = 0; j < 8; ++j) {
      poolA[j] += __shfl_xor(poolA[j], m, 64);
      poolB[j] += __shfl_xor(poolB[j], m, 64);
    }
  }
  if (l15 == 0) {
    #pragma unroll
    for (int j = 0; j < 8; ++j) {
      sTmp[wid][l4 * 8 + j] = poolA[j];
      sTmp[wid][32 + l4 * 8 + j] = poolB[j];
    }
  }
  __syncthreads();
  if (tid < En)
    out[(size_t)b * En + tid] =
        sTmp[0][tid] + sTmp[1][tid] + sTmp[2][tid] + sTmp[3][tid];
}

extern "C" void kernel_launch(void* const* d_in, const int* in_sizes, int n_in,
                              void* d_out, int out_size, void* d_ws, size_t ws_size,
                              hipStream_t stream) {
  const float* query       = (const float*)d_in[0];
  const float* keys        = (const float*)d_in[1];
  const int*   keys_length = (const int*)d_in[2];
  const float* W1 = (const float*)d_in[3];
  const float* b1 = (const float*)d_in[4];
  const float* W2 = (const float*)d_in[5];
  const float* b2 = (const float*)d_in[6];
  const float* W3 = (const float*)d_in[7];
  const float* b3 = (const float*)d_in[8];
  float* out = (float*)d_out;

  hipLaunchKernelGGL(din_prep, dim3(20), dim3(256), 0, stream, W1, W2);
  hipLaunchKernelGGL(din_main, dim3(Bn), dim3(256), 0, stream,
                     query, keys, keys_length, b1, b2, W3, b3, out);
}

// Round 10
// 67.643 us; speedup vs baseline: 1.6517x; 1.0623x over previous
//
#include <hip/hip_runtime.h>

// DIN attention pooling — round 10: R9 + 2-tile ILP per wave.
//   Wb[e][h] = (W1b-W1c)[e][h] + q_e*W1d[e][h];  qh[h] = b1[h] + q @ (W1a+W1c)
//   H = sig(K@Wb + qh); G = sig(H@W2 + b2); s = G@W3 + b3 (masked); out = s^T K
// Latency-bound at R9 (all pipes <45%, chain serial per tile). Two tiles in
// flight per wave (separate reg state + 2 LDS slabs): B's loads/MFMAs overlap
// A's sigmoid/LDS/reduce. Register bound stays (256,3) = 170 unified regs
// (R6/R8: budget <170 => catastrophic spill; R7/R9: (256,3) spill-free).

constexpr int Bn = 2048, Tn = 200, En = 64;
constexpr int HS_W  = 84;                // H slab stride (f16)
constexpr int HSLAB = 16 * HS_W + 48;    // 1392: covers row-15 aH2 read to 1388
constexpr int W2_W  = 104;               // W2T LDS stride (208B = 13 quads, odd)
constexpr int W2SZ  = 48 * W2_W + 32;    // pad: c=47 read overhangs to 5016

typedef _Float16 f16;
typedef _Float16 f16x8 __attribute__((ext_vector_type(8)));
typedef float f32x4 __attribute__((ext_vector_type(4)));

__device__ __align__(16) f16 g_wkf[80 * 64];    // [h][e]  W1b - W1c
__device__ __align__(16) f16 g_wqf[80 * 64];    // [h][e]  W1d
__device__ __align__(16) f16 g_wsumT[80 * 64];  // [h][e]  W1a + W1c
__device__ __align__(16) f16 g_w2t[48 * 96];    // [j][h]  W2^T, zeros j>=40 or h>=80

__device__ __forceinline__ float fsig(float x) {
  return __fdividef(1.0f, 1.0f + __expf(-x));
}

__global__ __launch_bounds__(256) void din_prep(const float* __restrict__ W1,
                                                const float* __restrict__ W2) {
  int idx = blockIdx.x * 256 + threadIdx.x;   // grid 20 -> 5120
  if (idx < 5120) {
    int h = idx >> 6, e = idx & 63;
    float wa = W1[e * 80 + h], wb = W1[(64 + e) * 80 + h];
    float wc = W1[(128 + e) * 80 + h], wd = W1[(192 + e) * 80 + h];
    g_wkf[idx] = (f16)(wb - wc);
    g_wqf[idx] = (f16)wd;
    g_wsumT[idx] = (f16)(wa + wc);
  }
  if (idx < 4608) {
    int j = idx / 96, h = idx - j * 96;
    g_w2t[idx] = (h < 80 && j < 40) ? (f16)W2[h * 40 + j] : (f16)0.0f;
  }
}

__global__ __launch_bounds__(256, 3) void din_main(
    const float* __restrict__ query,
    const float* __restrict__ keys,
    const int*   __restrict__ keys_length,
    const float* __restrict__ b1,
    const float* __restrict__ b2,
    const float* __restrict__ W3,
    const float* __restrict__ b3,
    float* __restrict__ out)
{
  __shared__ __align__(16) f16 sH[4][2][HSLAB];  // 22,272 B (2 slabs per wave)
  __shared__ __align__(16) f16 sW2[W2SZ];        // 10,048 B
  __shared__ float sSw[4][2][16];                //    512 B
  __shared__ float sTmp[4][64];                  //  1,024 B

  const int tid = threadIdx.x;
  const int lane = tid & 63;
  const int wid = tid >> 6;
  const int l15 = lane & 15;
  const int l4  = lane >> 4;

  const int b = blockIdx.x;
  const float* qp = query + (size_t)b * En;
  const float* kb = keys + (size_t)b * Tn * En;
  const int len = keys_length[b];
  const float b3v = b3[0];

  f16* hsA = sH[wid][0];
  f16* hsB = sH[wid][1];

  // ---- zero own slabs (cols 80..95 + pads must read 0.0 in L2 MFMAs) ----
  const f16x8 zf = (f16x8)(f16)0.0f;
  for (int i = lane * 8; i < HSLAB; i += 512) {
    *(f16x8*)&hsA[i] = zf;
    *(f16x8*)&hsB[i] = zf;
  }

  // ---- cooperative W2^T copy into LDS (stride 104) + zero the tail pad ----
  for (int i = tid; i < 576; i += 256) {
    int j = i / 12, hq = (i % 12) * 8;
    *(f16x8*)&sW2[j * W2_W + hq] = *(const f16x8*)&g_w2t[j * 96 + hq];
  }
  if (tid < 4) *(f16x8*)&sW2[48 * W2_W + tid * 8] = zf;
  __syncthreads();

  // ---- q fragments (f16) ----
  f16x8 qf0, qf1;
  {
    float4 qa = *(const float4*)(qp + l4 * 8);
    float4 qb = *(const float4*)(qp + l4 * 8 + 4);
    float4 qc = *(const float4*)(qp + 32 + l4 * 8);
    float4 qd = *(const float4*)(qp + 32 + l4 * 8 + 4);
    qf0 = (f16x8){(f16)qa.x,(f16)qa.y,(f16)qa.z,(f16)qa.w,
                  (f16)qb.x,(f16)qb.y,(f16)qb.z,(f16)qb.w};
    qf1 = (f16x8){(f16)qc.x,(f16)qc.y,(f16)qc.z,(f16)qc.w,
                  (f16)qd.x,(f16)qd.y,(f16)qd.z,(f16)qd.w};
  }

  // ---- qh[c] = b1[c] + q @ wsum[:,c] via VALU dot + shfl over l4 ----
  float qhv[5];
  #pragma unroll
  for (int n = 0; n < 5; ++n) {
    int c = n * 16 + l15;
    f16x8 ws0 = *(const f16x8*)&g_wsumT[c * 64 + l4 * 8];
    f16x8 ws1 = *(const f16x8*)&g_wsumT[c * 64 + 32 + l4 * 8];
    float p = 0.f;
    #pragma unroll
    for (int j = 0; j < 8; ++j)
      p += (float)qf0[j] * (float)ws0[j] + (float)qf1[j] * (float)ws1[j];
    p += __shfl_xor(p, 16, 64);
    p += __shfl_xor(p, 32, 64);
    qhv[n] = p + b1[c];
  }

  // ---- L1 B-fragments: Wb = wk + q*wqk (elementwise f16) ----
  f16x8 bf0[5], bf1[5];
  #pragma unroll
  for (int n = 0; n < 5; ++n) {
    int c = n * 16 + l15;
    bf0[n] = *(const f16x8*)&g_wkf[c * 64 + l4 * 8]
           + qf0 * *(const f16x8*)&g_wqf[c * 64 + l4 * 8];
    bf1[n] = *(const f16x8*)&g_wkf[c * 64 + 32 + l4 * 8]
           + qf1 * *(const f16x8*)&g_wqf[c * 64 + 32 + l4 * 8];
  }

  // ---- per-col constants for L2/L3 ----
  float b2v[3], w3v[3];
  #pragma unroll
  for (int n = 0; n < 3; ++n) {
    int c = n * 16 + l15;
    b2v[n] = (c < 40) ? b2[c] : 0.0f;
    w3v[n] = (c < 40) ? W3[c] : 0.0f;
  }

  float poolA[8] = {0,0,0,0,0,0,0,0};
  float poolB[8] = {0,0,0,0,0,0,0,0};

  // ---- this wave's tile range: 4/3/3/3 split of 13 tiles ----
  const int mts = (wid == 0) ? 0 : 3 * wid + 1;
  const int mte = mts + ((wid == 0) ? 4 : 3);

  int mt = mts;
  // ================= paired tiles: two independent chains in flight =========
  for (; mt + 1 < mte; mt += 2) {
    // ---- keys loads for both tiles (B's latency hides under A's compute) ---
    int rA = mt * 16 + l15;        const float* krA = kb + (rA < Tn ? rA : Tn - 1) * 64;
    int rB = (mt + 1) * 16 + l15;  const float* krB = kb + (rB < Tn ? rB : Tn - 1) * 64;
    float4 a0 = *(const float4*)(krA + l4 * 8);
    float4 a1 = *(const float4*)(krA + l4 * 8 + 4);
    float4 a2 = *(const float4*)(krA + 32 + l4 * 8);
    float4 a3 = *(const float4*)(krA + 32 + l4 * 8 + 4);
    float4 b0 = *(const float4*)(krB + l4 * 8);
    float4 b1_ = *(const float4*)(krB + l4 * 8 + 4);
    float4 b2_ = *(const float4*)(krB + 32 + l4 * 8);
    float4 b3_ = *(const float4*)(krB + 32 + l4 * 8 + 4);
    f16x8 kaA = (f16x8){(f16)a0.x,(f16)a0.y,(f16)a0.z,(f16)a0.w,
                        (f16)a1.x,(f16)a1.y,(f16)a1.z,(f16)a1.w};
    f16x8 kcA = (f16x8){(f16)a2.x,(f16)a2.y,(f16)a2.z,(f16)a2.w,
                        (f16)a3.x,(f16)a3.y,(f16)a3.z,(f16)a3.w};
    f16x8 kaB = (f16x8){(f16)b0.x,(f16)b0.y,(f16)b0.z,(f16)b0.w,
                        (f16)b1_.x,(f16)b1_.y,(f16)b1_.z,(f16)b1_.w};
    f16x8 kcB = (f16x8){(f16)b2_.x,(f16)b2_.y,(f16)b2_.z,(f16)b2_.w,
                        (f16)b3_.x,(f16)b3_.y,(f16)b3_.z,(f16)b3_.w};

    // ---- L1 both tiles (independent MFMA chains; compiler interleaves) ----
    #pragma unroll
    for (int n = 0; n < 5; ++n) {
      f32x4 accA = {0.f, 0.f, 0.f, 0.f};
      accA = __builtin_amdgcn_mfma_f32_16x16x32_f16(kaA, bf0[n], accA, 0, 0, 0);
      accA = __builtin_amdgcn_mfma_f32_16x16x32_f16(kcA, bf1[n], accA, 0, 0, 0);
      f32x4 accB = {0.f, 0.f, 0.f, 0.f};
      accB = __builtin_amdgcn_mfma_f32_16x16x32_f16(kaB, bf0[n], accB, 0, 0, 0);
      accB = __builtin_amdgcn_mfma_f32_16x16x32_f16(kcB, bf1[n], accB, 0, 0, 0);
      int c = n * 16 + l15;
      #pragma unroll
      for (int i = 0; i < 4; ++i) {
        hsA[(l4 * 4 + i) * HS_W + c] = (f16)fsig(accA[i] + qhv[n]);
        hsB[(l4 * 4 + i) * HS_W + c] = (f16)fsig(accB[i] + qhv[n]);
      }
    }

    // ---- L2 both tiles ----
    f16x8 aA0 = *(const f16x8*)&hsA[l15 * HS_W + l4 * 8];
    f16x8 aA1 = *(const f16x8*)&hsA[l15 * HS_W + 32 + l4 * 8];
    f16x8 aA2 = *(const f16x8*)&hsA[l15 * HS_W + 64 + l4 * 8];
    f16x8 aB0 = *(const f16x8*)&hsB[l15 * HS_W + l4 * 8];
    f16x8 aB1 = *(const f16x8*)&hsB[l15 * HS_W + 32 + l4 * 8];
    f16x8 aB2 = *(const f16x8*)&hsB[l15 * HS_W + 64 + l4 * 8];
    float scA[4] = {0.f, 0.f, 0.f, 0.f};
    float scB[4] = {0.f, 0.f, 0.f, 0.f};
    #pragma unroll
    for (int n = 0; n < 3; ++n) {
      int c = n * 16 + l15;
      f16x8 w0 = *(const f16x8*)&sW2[c * W2_W + l4 * 8];
      f16x8 w1 = *(const f16x8*)&sW2[c * W2_W + 32 + l4 * 8];
      f16x8 w2 = *(const f16x8*)&sW2[c * W2_W + 64 + l4 * 8];
      f32x4 accA = {0.f, 0.f, 0.f, 0.f};
      accA = __builtin_amdgcn_mfma_f32_16x16x32_f16(aA0, w0, accA, 0, 0, 0);
      accA = __builtin_amdgcn_mfma_f32_16x16x32_f16(aA1, w1, accA, 0, 0, 0);
      accA = __builtin_amdgcn_mfma_f32_16x16x32_f16(aA2, w2, accA, 0, 0, 0);
      f32x4 accB = {0.f, 0.f, 0.f, 0.f};
      accB = __builtin_amdgcn_mfma_f32_16x16x32_f16(aB0, w0, accB, 0, 0, 0);
      accB = __builtin_amdgcn_mfma_f32_16x16x32_f16(aB1, w1, accB, 0, 0, 0);
      accB = __builtin_amdgcn_mfma_f32_16x16x32_f16(aB2, w2, accB, 0, 0, 0);
      #pragma unroll
      for (int i = 0; i < 4; ++i) {
        scA[i] += fsig(accA[i] + b2v[n]) * w3v[n];
        scB[i] += fsig(accB[i] + b2v[n]) * w3v[n];
      }
    }
    // ---- joint shfl reduce over l15 (8 values through 4 levels) ----
    #pragma unroll
    for (int m = 1; m < 16; m <<= 1) {
      #pragma unroll
      for (int i = 0; i < 4; ++i) {
        scA[i] += __shfl_xor(scA[i], m, 64);
        scB[i] += __shfl_xor(scB[i], m, 64);
      }
    }
    if (l15 == 0) {
      #pragma unroll
      for (int i = 0; i < 4; ++i) {
        int rrA = mt * 16 + l4 * 4 + i;
        int rrB = (mt + 1) * 16 + l4 * 4 + i;
        sSw[wid][0][l4 * 4 + i] = (rrA < len) ? scA[i] + b3v : 0.0f;
        sSw[wid][1][l4 * 4 + i] = (rrB < len) ? scB[i] + b3v : 0.0f;
      }
    }
    float svA = sSw[wid][0][l15];
    float svB = sSw[wid][1][l15];
    #pragma unroll
    for (int j = 0; j < 8; ++j) {
      poolA[j] += svA * (float)kaA[j] + svB * (float)kaB[j];
      poolB[j] += svA * (float)kcA[j] + svB * (float)kcB[j];
    }
  }

  // ================= leftover single tile =================
  if (mt < mte) {
    int r = mt * 16 + l15; const float* kr = kb + (r < Tn ? r : Tn - 1) * 64;
    float4 a0 = *(const float4*)(kr + l4 * 8);
    float4 a1 = *(const float4*)(kr + l4 * 8 + 4);
    float4 a2 = *(const float4*)(kr + 32 + l4 * 8);
    float4 a3 = *(const float4*)(kr + 32 + l4 * 8 + 4);
    f16x8 ka = (f16x8){(f16)a0.x,(f16)a0.y,(f16)a0.z,(f16)a0.w,
                       (f16)a1.x,(f16)a1.y,(f16)a1.z,(f16)a1.w};
    f16x8 kc = (f16x8){(f16)a2.x,(f16)a2.y,(f16)a2.z,(f16)a2.w,
                       (f16)a3.x,(f16)a3.y,(f16)a3.z,(f16)a3.w};
    #pragma unroll
    for (int n = 0; n < 5; ++n) {
      f32x4 acc = {0.f, 0.f, 0.f, 0.f};
      acc = __builtin_amdgcn_mfma_f32_16x16x32_f16(ka, bf0[n], acc, 0, 0, 0);
      acc = __builtin_amdgcn_mfma_f32_16x16x32_f16(kc, bf1[n], acc, 0, 0, 0);
      int c = n * 16 + l15;
      #pragma unroll
      for (int i = 0; i < 4; ++i)
        hsA[(l4 * 4 + i) * HS_W + c] = (f16)fsig(acc[i] + qhv[n]);
    }
    f16x8 aH0 = *(const f16x8*)&hsA[l15 * HS_W + l4 * 8];
    f16x8 aH1 = *(const f16x8*)&hsA[l15 * HS_W + 32 + l4 * 8];
    f16x8 aH2 = *(const f16x8*)&hsA[l15 * HS_W + 64 + l4 * 8];
    float sc[4] = {0.f, 0.f, 0.f, 0.f};
    #pragma unroll
    for (int n = 0; n < 3; ++n) {
      int c = n * 16 + l15;
      f32x4 acc = {0.f, 0.f, 0.f, 0.f};
      acc = __builtin_amdgcn_mfma_f32_16x16x32_f16(aH0, *(const f16x8*)&sW2[c * W2_W + l4 * 8], acc, 0, 0, 0);
      acc = __builtin_amdgcn_mfma_f32_16x16x32_f16(aH1, *(const f16x8*)&sW2[c * W2_W + 32 + l4 * 8], acc, 0, 0, 0);
      acc = __builtin_amdgcn_mfma_f32_16x16x32_f16(aH2, *(const f16x8*)&sW2[c * W2_W + 64 + l4 * 8], acc, 0, 0, 0);
      #pragma unroll
      for (int i = 0; i < 4; ++i)
        sc[i] += fsig(acc[i] + b2v[n]) * w3v[n];
    }
    #pragma unroll
    for (int m = 1; m < 16; m <<= 1) {
      #pragma unroll
      for (int i = 0; i < 4; ++i) sc[i] += __shfl_xor(sc[i], m, 64);
    }
    if (l15 == 0) {
      #pragma unroll
      for (int i = 0; i < 4; ++i) {
        int rr = mt * 16 + l4 * 4 + i;
        sSw[wid][0][l4 * 4 + i] = (rr < len) ? sc[i] + b3v : 0.0f;
      }
    }
    float sv = sSw[wid][0][l15];
    #pragma unroll
    for (int j = 0; j < 8; ++j) {
      poolA[j] += sv * (float)ka[j];
      poolB[j] += sv * (float)kc[j];
    }
  }

  // ---- reduce pooling over the 16 rows (l15) of each l4 group ----
  #pragma unroll
  for (int m = 1; m < 16; m <<= 1) {
    #pragma unroll
    for (int j = 0; j < 8; ++j) {
      poolA[j] += __shfl_xor(poolA[j], m, 64);
      poolB[j] += __shfl_xor(poolB[j], m, 64);
    }
  }
  if (l15 == 0) {
    #pragma unroll
    for (int j = 0; j < 8; ++j) {
      sTmp[wid][l4 * 8 + j] = poolA[j];
      sTmp[wid][32 + l4 * 8 + j] = poolB[j];
    }
  }
  __syncthreads();
  if (tid < En)
    out[(size_t)b * En + tid] =
        sTmp[0][tid] + sTmp[1][tid] + sTmp[2][tid] + sTmp[3][tid];
}

extern "C" void kernel_launch(void* const* d_in, const int* in_sizes, int n_in,
                              void* d_out, int out_size, void* d_ws, size_t ws_size,
                              hipStream_t stream) {
  const float* query       = (const float*)d_in[0];
  const float* keys        = (const float*)d_in[1];
  const int*   keys_length = (const int*)d_in[2];
  const float* W1 = (const float*)d_in[3];
  const float* b1 = (const float*)d_in[4];
  const float* W2 = (const float*)d_in[5];
  const float* b2 = (const float*)d_in[6];
  const float* W3 = (const float*)d_in[7];
  const float* b3 = (const float*)d_in[8];
  float* out = (float*)d_out;

  hipLaunchKernelGGL(din_prep, dim3(20), dim3(256), 0, stream, W1, W2);
  hipLaunchKernelGGL(din_main, dim3(Bn), dim3(256), 0, stream,
                     query, keys, keys_length, b1, b2, W3, b3, out);
}